// Round 2
// baseline (283.109 us; speedup 1.0000x reference)
//
#include <hip/hip_runtime.h>
#include <math.h>

#define BB 8
#define NN 2048
#define FF 64

// ---------------------------------------------------------------------------
// K1: Wh = h @ W  (B*N x 64) ; f1 = Wh@a1 ; f2 = Wh@a2
// block = 256 threads = 4 rows x 64 features; each wave owns one row.
// ---------------------------------------------------------------------------
__global__ __launch_bounds__(256) void k1_gemm(const float* __restrict__ h,
                                               const float* __restrict__ W,
                                               const float* __restrict__ a,
                                               float* __restrict__ Wh,
                                               float* __restrict__ f1,
                                               float* __restrict__ f2) {
  __shared__ float Wl[FF * FF];
  __shared__ float hl[4 * FF];
  __shared__ float a1l[FF], a2l[FF];
  const int tid = threadIdx.x;
  const int r = tid >> 6, f = tid & 63;
  for (int i = tid; i < FF * FF; i += 256) Wl[i] = W[i];
  if (tid < FF) { a1l[tid] = a[tid]; a2l[tid] = a[FF + tid]; }
  const int row0 = blockIdx.x * 4;
  for (int i = tid; i < 4 * FF; i += 256) hl[i] = h[(size_t)row0 * FF + i];
  __syncthreads();
  const int row = row0 + r;
  float acc = 0.f;
#pragma unroll
  for (int k = 0; k < FF; ++k) acc = fmaf(hl[r * FF + k], Wl[k * FF + f], acc);
  Wh[(size_t)row * FF + f] = acc;
  float v1 = acc * a1l[f];
  float v2 = acc * a2l[f];
#pragma unroll
  for (int o = 32; o > 0; o >>= 1) {
    v1 += __shfl_xor(v1, o, 64);
    v2 += __shfl_xor(v2, o, 64);
  }
  if (f == 0) { f1[row] = v1; f2[row] = v2; }
}

// ---------------------------------------------------------------------------
// K2: per-batch bitonic sort of (f2, index) ascending. One block per batch.
// Epilogue (keys still in LDS): exp weights for both branches (double) and
// per-row split point p0 via LDS binary search (saves K4 the L2 round-trips).
// ---------------------------------------------------------------------------
__global__ __launch_bounds__(1024) void k2_sort(const float* __restrict__ f2,
                                                const float* __restrict__ f1,
                                                int* __restrict__ idxs,
                                                double* __restrict__ wlo,
                                                double* __restrict__ whi,
                                                int* __restrict__ p0arr) {
  __shared__ float key[NN];
  __shared__ int val[NN];
  const int b = blockIdx.x, tid = threadIdx.x;
  for (int i = tid; i < NN; i += 1024) { key[i] = f2[b * NN + i]; val[i] = i; }
  __syncthreads();
  for (int k = 2; k <= NN; k <<= 1) {
    for (int j = k >> 1; j > 0; j >>= 1) {
      for (int i = tid; i < NN; i += 1024) {
        const int ixj = i ^ j;
        if (ixj > i) {
          const bool up = ((i & k) == 0);
          const float ki = key[i], kj = key[ixj];
          if ((ki > kj) == up) {
            key[i] = kj; key[ixj] = ki;
            const int vi = val[i]; val[i] = val[ixj]; val[ixj] = vi;
          }
        }
      }
      __syncthreads();
    }
  }
  // sorted: key[q] ascending, val[q] = original row index
  for (int i = tid; i < NN; i += 1024) {
    idxs[b * NN + i] = val[i];
    const double k = (double)key[i];
    wlo[b * NN + i] = exp(0.01 * k);
    whi[b * NN + i] = exp(k);
  }
  for (int i = tid; i < NN; i += 1024) {
    const float t = -f1[b * NN + i];
    int lo = 0, hi = NN;
    while (lo < hi) { const int m = (lo + hi) >> 1; if (key[m] < t) lo = m + 1; else hi = m; }
    p0arr[b * NN + i] = lo;  // first sorted index with f2 >= -f1
  }
}

// ---------------------------------------------------------------------------
// K3: scans over sorted order. grid = (pass, batch), block = 1024 =
// 16 chunks x 64 features. Wave = one chunk, lanes = consecutive features ->
// Wh gathers are 256B coalesced lines. Double accumulation, ONE barrier.
//   pass 0: P_lo[b][p][f] = sum_{q<p}  wlo[q] * Wh[idx_q][f]  (exclusive)
//   pass 1: S_hi[b][p][f] = sum_{q>=p} whi[q] * Wh[idx_q][f]  (inclusive)
// plus the scalar (weight-only) scans Pz / Sz written by lane f==0.
// ---------------------------------------------------------------------------
__global__ __launch_bounds__(1024) void k3_scan(const float* __restrict__ Wh,
                                                const int* __restrict__ idxs,
                                                const double* __restrict__ wlo,
                                                const double* __restrict__ whi,
                                                float* __restrict__ P_lo,
                                                float* __restrict__ S_hi,
                                                float* __restrict__ Pz,
                                                float* __restrict__ Sz) {
  __shared__ double sl[16][64];
  __shared__ double slz[16];
  const int pass = blockIdx.x;  // 0 = lo prefix, 1 = hi suffix
  const int b = blockIdx.y;
  const int tid = threadIdx.x;
  const int f = tid & 63, c = tid >> 6;
  const int q0 = c * 128;
  const int* __restrict__ idb = idxs + b * NN;
  const float* __restrict__ Whb = Wh + (size_t)b * NN * FF;

  if (pass == 0) {
    const double* __restrict__ wv = wlo + b * NN;
    double s = 0.0, sz = 0.0;
#pragma unroll 4
    for (int i = 0; i < 128; ++i) {
      const int q = q0 + i;
      const double w = wv[q];
      s += w * (double)Whb[(size_t)idb[q] * FF + f];
      sz += w;
    }
    sl[c][f] = s; if (f == 0) slz[c] = sz;
    __syncthreads();
    double run = 0.0, runz = 0.0;
    for (int cc = 0; cc < c; ++cc) { run += sl[cc][f]; runz += slz[cc]; }
    float* __restrict__ P = P_lo + (size_t)b * (NN + 1) * FF;
    float* __restrict__ PzB = Pz + (size_t)b * (NN + 1);
#pragma unroll 4
    for (int i = 0; i < 128; ++i) {
      const int q = q0 + i;
      P[(size_t)q * FF + f] = (float)run;
      if (f == 0) PzB[q] = (float)runz;
      const double w = wv[q];
      run += w * (double)Whb[(size_t)idb[q] * FF + f];
      runz += w;
    }
    if (c == 15) { P[(size_t)NN * FF + f] = (float)run; if (f == 0) PzB[NN] = (float)runz; }
  } else {
    const double* __restrict__ wv = whi + b * NN;
    double s = 0.0, sz = 0.0;
#pragma unroll 4
    for (int i = 0; i < 128; ++i) {
      const int q = q0 + i;
      const double w = wv[q];
      s += w * (double)Whb[(size_t)idb[q] * FF + f];
      sz += w;
    }
    sl[c][f] = s; if (f == 0) slz[c] = sz;
    __syncthreads();
    double run = 0.0, runz = 0.0;
    for (int cc = c + 1; cc < 16; ++cc) { run += sl[cc][f]; runz += slz[cc]; }
    float* __restrict__ S = S_hi + (size_t)b * (NN + 1) * FF;
    float* __restrict__ SzB = Sz + (size_t)b * (NN + 1);
#pragma unroll 4
    for (int i = 127; i >= 0; --i) {
      const int q = q0 + i;
      const double w = wv[q];
      run += w * (double)Whb[(size_t)idb[q] * FF + f];
      runz += w;
      S[(size_t)q * FF + f] = (float)run;
      if (f == 0) SzB[q] = (float)runz;
    }
    if (c == 15) { S[(size_t)NN * FF + f] = 0.f; if (f == 0) SzB[NN] = 0.f; }
  }
}

// ---------------------------------------------------------------------------
// K4: combine. 4 rows x 64 feats per block; p0 precomputed -> pure loads.
// ---------------------------------------------------------------------------
__global__ __launch_bounds__(256) void k4_out(const float* __restrict__ f1,
                                              const int* __restrict__ p0arr,
                                              const float* __restrict__ S_hi,
                                              const float* __restrict__ P_lo,
                                              const float* __restrict__ Sz,
                                              const float* __restrict__ Pz,
                                              float* __restrict__ out) {
  const int tid = threadIdx.x;
  const int r = tid >> 6, f = tid & 63;
  const int row = blockIdx.x * 4 + r;
  const int b = row >> 11;  // N = 2048
  const float f1v = f1[row];
  const int p0 = p0arr[row];
  const double w1 = exp((double)f1v);
  const double w2 = exp(0.01 * (double)f1v);
  const size_t bp = (size_t)b * (NN + 1) + p0;
  const double num = w1 * (double)S_hi[bp * FF + f] + w2 * (double)P_lo[bp * FF + f];
  const double Z = w1 * (double)Sz[bp] + w2 * (double)Pz[bp];
  out[(size_t)row * FF + f] = (float)(num / Z);
}

extern "C" void kernel_launch(void* const* d_in, const int* in_sizes, int n_in,
                              void* d_out, int out_size, void* d_ws, size_t ws_size,
                              hipStream_t stream) {
  const float* h = (const float*)d_in[0];
  // d_in[1] = adj : unused by the reference (all-ones, never read)
  const float* W = (const float*)d_in[2];
  const float* a = (const float*)d_in[3];
  float* out = (float*)d_out;

  float* ws = (float*)d_ws;
  size_t o = 0;
  float* Wh  = ws + o; o += (size_t)BB * NN * FF;         // 1,048,576
  float* f1  = ws + o; o += (size_t)BB * NN;              // 16,384
  float* f2  = ws + o; o += (size_t)BB * NN;
  int*   idxs = (int*)(ws + o); o += (size_t)BB * NN;
  double* wlo = (double*)(ws + o); o += (size_t)BB * NN * 2;  // 8B each
  double* whi = (double*)(ws + o); o += (size_t)BB * NN * 2;
  int*   p0arr = (int*)(ws + o); o += (size_t)BB * NN;
  float* S_hi = ws + o; o += (size_t)BB * (NN + 1) * FF;  // 1,049,088
  float* P_lo = ws + o; o += (size_t)BB * (NN + 1) * FF;
  float* Sz  = ws + o; o += (size_t)BB * (NN + 1);
  float* Pz  = ws + o; o += (size_t)BB * (NN + 1);

  k1_gemm<<<BB * NN / 4, 256, 0, stream>>>(h, W, a, Wh, f1, f2);
  k2_sort<<<BB, 1024, 0, stream>>>(f2, f1, idxs, wlo, whi, p0arr);
  dim3 g3(2, BB);
  k3_scan<<<g3, 1024, 0, stream>>>(Wh, idxs, wlo, whi, P_lo, S_hi, Pz, Sz);
  k4_out<<<BB * NN / 4, 256, 0, stream>>>(f1, p0arr, S_hi, P_lo, Sz, Pz, out);
}

// Round 4
// 220.582 us; speedup vs baseline: 1.2835x; 1.2835x over previous
//
#include <hip/hip_runtime.h>
#include <math.h>

#define BB 8
#define NN 2048
#define FF 64

// ---------------------------------------------------------------------------
// K1: Wh = h @ W  (B*N x 64) ; f1 = Wh@a1 ; f2 = Wh@a2
// block = 256 threads = 4 rows x 64 features; each wave owns one row.
// ---------------------------------------------------------------------------
__global__ __launch_bounds__(256) void k1_gemm(const float* __restrict__ h,
                                               const float* __restrict__ W,
                                               const float* __restrict__ a,
                                               float* __restrict__ Wh,
                                               float* __restrict__ f1,
                                               float* __restrict__ f2) {
  __shared__ float Wl[FF * FF];
  __shared__ float hl[4 * FF];
  __shared__ float a1l[FF], a2l[FF];
  const int tid = threadIdx.x;
  const int r = tid >> 6, f = tid & 63;
  for (int i = tid; i < FF * FF; i += 256) Wl[i] = W[i];
  if (tid < FF) { a1l[tid] = a[tid]; a2l[tid] = a[FF + tid]; }
  const int row0 = blockIdx.x * 4;
  for (int i = tid; i < 4 * FF; i += 256) hl[i] = h[(size_t)row0 * FF + i];
  __syncthreads();
  const int row = row0 + r;
  float acc = 0.f;
#pragma unroll
  for (int k = 0; k < FF; ++k) acc = fmaf(hl[r * FF + k], Wl[k * FF + f], acc);
  Wh[(size_t)row * FF + f] = acc;
  float v1 = acc * a1l[f];
  float v2 = acc * a2l[f];
#pragma unroll
  for (int o = 32; o > 0; o >>= 1) {
    v1 += __shfl_xor(v1, o, 64);
    v2 += __shfl_xor(v2, o, 64);
  }
  if (f == 0) { f1[row] = v1; f2[row] = v2; }
}

// ---------------------------------------------------------------------------
// K2: per-batch COUNTING sort (near-sort; within-bucket order irrelevant:
// bucket width ~5e-3 -> relative weight perturbation ~0.5% on boundary
// elements only -> output error ~1e-5). ~5 barriers vs bitonic's 66.
// Epilogue: float exp weights in sorted order + per-row split p0 via LDS
// binary search (array monotone across buckets -> same delta-bound).
// ---------------------------------------------------------------------------
__global__ __launch_bounds__(1024) void k2_sort(const float* __restrict__ f2,
                                                const float* __restrict__ f1,
                                                int* __restrict__ idxs,
                                                float* __restrict__ wlo,
                                                float* __restrict__ whi,
                                                int* __restrict__ p0arr) {
  __shared__ float skey[NN];
  __shared__ int sval[NN];
  __shared__ int start[NN];
  __shared__ float mnb[16], mxb[16];
  __shared__ int wsum[16];
  const int b = blockIdx.x, tid = threadIdx.x;
  const int lane = tid & 63, wvi = tid >> 6;
  const float k0 = f2[b * NN + tid];
  const float k1 = f2[b * NN + 1024 + tid];
  float mn = fminf(k0, k1), mx = fmaxf(k0, k1);
#pragma unroll
  for (int o = 32; o > 0; o >>= 1) {
    mn = fminf(mn, __shfl_xor(mn, o, 64));
    mx = fmaxf(mx, __shfl_xor(mx, o, 64));
  }
  if (lane == 0) { mnb[wvi] = mn; mxb[wvi] = mx; }
  start[tid] = 0; start[tid + 1024] = 0;
  __syncthreads();
  float gmn = mnb[0], gmx = mxb[0];
#pragma unroll
  for (int c = 1; c < 16; ++c) { gmn = fminf(gmn, mnb[c]); gmx = fmaxf(gmx, mxb[c]); }
  const float scale = 2047.0f / fmaxf(gmx - gmn, 1e-12f);
  int bk0 = (int)((k0 - gmn) * scale); bk0 = min(max(bk0, 0), 2047);
  int bk1 = (int)((k1 - gmn) * scale); bk1 = min(max(bk1, 0), 2047);
  atomicAdd(&start[bk0], 1);
  atomicAdd(&start[bk1], 1);
  __syncthreads();
  // exclusive scan of the 2048 counts (2 per thread)
  const int c0 = start[2 * tid], c1 = start[2 * tid + 1];
  int s = c0 + c1;
#pragma unroll
  for (int o = 1; o < 64; o <<= 1) {
    const int t = __shfl_up(s, o, 64);
    if (lane >= o) s += t;
  }
  if (lane == 63) wsum[wvi] = s;
  __syncthreads();  // wsum visible; all counts already read
  int wbase = 0;
  for (int w = 0; w < wvi; ++w) wbase += wsum[w];
  const int inc = wbase + s;
  const int e1 = inc - c1, e0 = e1 - c0;
  start[2 * tid] = e0; start[2 * tid + 1] = e1;
  __syncthreads();
  // scatter
  const int p = atomicAdd(&start[bk0], 1);
  skey[p] = k0; sval[p] = tid;
  const int p2 = atomicAdd(&start[bk1], 1);
  skey[p2] = k1; sval[p2] = 1024 + tid;
  __syncthreads();
  for (int i = tid; i < NN; i += 1024) {
    idxs[b * NN + i] = sval[i];
    const float kk = skey[i];
    wlo[b * NN + i] = expf(0.01f * kk);
    whi[b * NN + i] = expf(kk);
  }
  for (int i = tid; i < NN; i += 1024) {
    const float t = -f1[b * NN + i];
    int lo = 0, hi = NN;
    while (lo < hi) { const int m = (lo + hi) >> 1; if (skey[m] < t) lo = m + 1; else hi = m; }
    p0arr[b * NN + i] = lo;
  }
}

// ---------------------------------------------------------------------------
// K3a: per-(pass,b,chunk,sub) partial sums. grid (16,8,2), 256 thr = 4 subs
// x 64 feats; each thread sums 32 rows (double). k = c*4+sub in [0,64).
// ---------------------------------------------------------------------------
__global__ __launch_bounds__(256) void k3a(const float* __restrict__ Wh,
                                           const int* __restrict__ idxs,
                                           const float* __restrict__ wlo,
                                           const float* __restrict__ whi,
                                           double* __restrict__ part,
                                           double* __restrict__ zpart) {
  const int c = blockIdx.x, b = blockIdx.y, pass = blockIdx.z;
  const int tid = threadIdx.x, f = tid & 63, sub = tid >> 6;
  const int q0 = c * 128 + sub * 32;
  const int* __restrict__ idb = idxs + b * NN;
  const float* __restrict__ wv = (pass ? whi : wlo) + b * NN;
  const float* __restrict__ Whb = Wh + (size_t)b * NN * FF;
  double s = 0.0, sz = 0.0;
#pragma unroll 8
  for (int i = 0; i < 32; ++i) {
    const int q = q0 + i;
    const float w = wv[q];
    s += (double)w * (double)Whb[(size_t)idb[q] * FF + f];
    sz += (double)w;
  }
  const int k = c * 4 + sub;
  part[(((size_t)(pass * 8 + b)) * 64 + k) * 64 + f] = s;
  if (f == 0) zpart[(size_t)(pass * 8 + b) * 64 + k] = sz;
}

// ---------------------------------------------------------------------------
// K3b: scan the 64 sub-partials per (pass,b,f). grid (2,8) x 64 threads.
// pass0: base[k] = sum_{k'<k}; pass1: base[k] = sum_{k'>k}. Coalesced 512B.
// ---------------------------------------------------------------------------
__global__ __launch_bounds__(64) void k3b(const double* __restrict__ part,
                                          const double* __restrict__ zpart,
                                          double* __restrict__ base,
                                          double* __restrict__ zbase) {
  const int pass = blockIdx.x, b = blockIdx.y, f = threadIdx.x;
  const double* __restrict__ P = part + ((size_t)(pass * 8 + b)) * 64 * 64;
  double* __restrict__ Bs = base + ((size_t)(pass * 8 + b)) * 64 * 64;
  const double* __restrict__ Zp = zpart + (size_t)(pass * 8 + b) * 64;
  double* __restrict__ Zb = zbase + (size_t)(pass * 8 + b) * 64;
  double run = 0.0, runz = 0.0;
  if (pass == 0) {
    for (int k = 0; k < 64; ++k) {
      Bs[k * 64 + f] = run; run += P[k * 64 + f];
      if (f == 0) { Zb[k] = runz; } runz += Zp[k];
    }
  } else {
    for (int k = 63; k >= 0; --k) {
      Bs[k * 64 + f] = run; run += P[k * 64 + f];
      if (f == 0) { Zb[k] = runz; } runz += Zp[k];
    }
  }
}

// ---------------------------------------------------------------------------
// K3c: final sweep. grid (16,8,2), 256 thr; each thread sweeps its 32 rows
// from the precomputed double base, writing float P_lo/S_hi (+Pz/Sz lane 0).
// ---------------------------------------------------------------------------
__global__ __launch_bounds__(256) void k3c(const float* __restrict__ Wh,
                                           const int* __restrict__ idxs,
                                           const float* __restrict__ wlo,
                                           const float* __restrict__ whi,
                                           const double* __restrict__ base,
                                           const double* __restrict__ zbase,
                                           float* __restrict__ P_lo,
                                           float* __restrict__ S_hi,
                                           float* __restrict__ Pz,
                                           float* __restrict__ Sz) {
  const int c = blockIdx.x, b = blockIdx.y, pass = blockIdx.z;
  const int tid = threadIdx.x, f = tid & 63, sub = tid >> 6;
  const int q0 = c * 128 + sub * 32;
  const int k = c * 4 + sub;
  const int* __restrict__ idb = idxs + b * NN;
  const float* __restrict__ wv = (pass ? whi : wlo) + b * NN;
  const float* __restrict__ Whb = Wh + (size_t)b * NN * FF;
  double run = base[(((size_t)(pass * 8 + b)) * 64 + k) * 64 + f];
  double runz = zbase[(size_t)(pass * 8 + b) * 64 + k];
  if (pass == 0) {
    float* __restrict__ P = P_lo + (size_t)b * (NN + 1) * FF;
    float* __restrict__ PzB = Pz + (size_t)b * (NN + 1);
#pragma unroll 8
    for (int i = 0; i < 32; ++i) {
      const int q = q0 + i;
      P[(size_t)q * FF + f] = (float)run;
      if (f == 0) PzB[q] = (float)runz;
      const float w = wv[q];
      run += (double)w * (double)Whb[(size_t)idb[q] * FF + f];
      runz += (double)w;
    }
    if (c == 15 && sub == 3) { P[(size_t)NN * FF + f] = (float)run; if (f == 0) PzB[NN] = (float)runz; }
  } else {
    float* __restrict__ S = S_hi + (size_t)b * (NN + 1) * FF;
    float* __restrict__ SzB = Sz + (size_t)b * (NN + 1);
#pragma unroll 8
    for (int i = 31; i >= 0; --i) {
      const int q = q0 + i;
      const float w = wv[q];
      run += (double)w * (double)Whb[(size_t)idb[q] * FF + f];
      runz += (double)w;
      S[(size_t)q * FF + f] = (float)run;
      if (f == 0) SzB[q] = (float)runz;
    }
    if (c == 15 && sub == 3) { S[(size_t)NN * FF + f] = 0.f; if (f == 0) SzB[NN] = 0.f; }
  }
}

// ---------------------------------------------------------------------------
// K4: combine. 4 rows x 64 feats per block; all-float math.
// ---------------------------------------------------------------------------
__global__ __launch_bounds__(256) void k4_out(const float* __restrict__ f1,
                                              const int* __restrict__ p0arr,
                                              const float* __restrict__ S_hi,
                                              const float* __restrict__ P_lo,
                                              const float* __restrict__ Sz,
                                              const float* __restrict__ Pz,
                                              float* __restrict__ out) {
  const int tid = threadIdx.x;
  const int r = tid >> 6, f = tid & 63;
  const int row = blockIdx.x * 4 + r;
  const int b = row >> 11;  // N = 2048
  const float f1v = f1[row];
  const int p0 = p0arr[row];
  const float w1 = expf(f1v);
  const float w2 = expf(0.01f * f1v);
  const size_t bp = (size_t)b * (NN + 1) + p0;
  const float num = w1 * S_hi[bp * FF + f] + w2 * P_lo[bp * FF + f];
  const float Z = w1 * Sz[bp] + w2 * Pz[bp];
  out[(size_t)row * FF + f] = num / Z;
}

extern "C" void kernel_launch(void* const* d_in, const int* in_sizes, int n_in,
                              void* d_out, int out_size, void* d_ws, size_t ws_size,
                              hipStream_t stream) {
  const float* h = (const float*)d_in[0];
  // d_in[1] = adj : unused by the reference (all-ones, never read)
  const float* W = (const float*)d_in[2];
  const float* a = (const float*)d_in[3];
  float* out = (float*)d_out;

  float* ws = (float*)d_ws;
  size_t o = 0;
  // doubles first (8B alignment from base)
  double* part  = (double*)(ws + o); o += (size_t)2 * BB * 64 * 64 * 2;  // 65536 dbl
  double* zpart = (double*)(ws + o); o += (size_t)2 * BB * 64 * 2;       // 1024 dbl
  double* base  = (double*)(ws + o); o += (size_t)2 * BB * 64 * 64 * 2;
  double* zbase = (double*)(ws + o); o += (size_t)2 * BB * 64 * 2;
  float* Wh   = ws + o; o += (size_t)BB * NN * FF;
  float* f1   = ws + o; o += (size_t)BB * NN;
  float* f2   = ws + o; o += (size_t)BB * NN;
  int*   idxs = (int*)(ws + o); o += (size_t)BB * NN;
  float* wlo  = ws + o; o += (size_t)BB * NN;
  float* whi  = ws + o; o += (size_t)BB * NN;
  int*   p0arr = (int*)(ws + o); o += (size_t)BB * NN;
  float* S_hi = ws + o; o += (size_t)BB * (NN + 1) * FF;
  float* P_lo = ws + o; o += (size_t)BB * (NN + 1) * FF;
  float* Sz   = ws + o; o += (size_t)BB * (NN + 1);
  float* Pz   = ws + o; o += (size_t)BB * (NN + 1);

  k1_gemm<<<BB * NN / 4, 256, 0, stream>>>(h, W, a, Wh, f1, f2);
  k2_sort<<<BB, 1024, 0, stream>>>(f2, f1, idxs, wlo, whi, p0arr);
  dim3 g3(16, BB, 2);
  k3a<<<g3, 256, 0, stream>>>(Wh, idxs, wlo, whi, part, zpart);
  dim3 gb(2, BB);
  k3b<<<gb, 64, 0, stream>>>(part, zpart, base, zbase);
  k3c<<<g3, 256, 0, stream>>>(Wh, idxs, wlo, whi, base, zbase, P_lo, S_hi, Pz, Sz);
  k4_out<<<BB * NN / 4, 256, 0, stream>>>(f1, p0arr, S_hi, P_lo, Sz, Pz, out);
}